// Round 1
// baseline (755.240 us; speedup 1.0000x reference)
//
#include <hip/hip_runtime.h>

#define NB 2
#define NPTS 8192
#define NQ 4096
#define MTOT 8192      // NB*NQ
#define SP 16
#define SD 32
#define CIN 32
#define CP 32
#define CF 64
#define NROI 128       // NB*64
#define RADIUS_C 0.8f
#define MIN_R_C 0.01f
#define DIV_COEF_C 10.0f
#define GRID_MLP 1024

// ---------------- device-global scratch (fully rewritten every call) -------
__device__ int   g_idx_p[MTOT * SP];
__device__ int   g_empty_p[MTOT];
__device__ float g_x0p[MTOT * SP * CP];
__device__ float g_x1p[MTOT * SP * CP];
__device__ int   g_idx_d[MTOT * SD];
__device__ int   g_empty_d[MTOT];
__device__ float g_x0f[(size_t)MTOT * SD * CF];   // 64 MB
__device__ float g_x1f[(size_t)MTOT * SD * CF];   // 64 MB
__device__ float g_ps[GRID_MLP * CF];             // per-block channel sums
__device__ float g_pq[GRID_MLP * CF];             // per-block channel sumsq
__device__ float g_bnscale[4][CF];                // 0=p0 1=p1 2=f0 3=f1
__device__ float g_bnshift[4][CF];
__device__ float g_pdot[MTOT];
__device__ float g_rroi[NROI];

// ---------------- new_xyz output is rois flattened -------------------------
__global__ void copy_xyz_kernel(const float* __restrict__ rois, float* __restrict__ out) {
    int i = blockIdx.x * 256 + threadIdx.x;
    if (i < MTOT * 3) out[i] = rois[i];
}

// ---------------- ball query: one wave per query, index-ordered scan -------
// NS==SP: pred pass (fixed RADIUS) -> g_idx_p/g_empty_p
// NS==SD: deform pass (per-roi radius g_rroi) -> g_idx_d/g_empty_d
template <int NS>
__global__ void bq_kernel(const float* __restrict__ xyz, const float* __restrict__ newxyz) {
    __shared__ float l_xyz[NPTS * 3];   // 96 KB (gfx950: 160 KB/WG available)
    int tid = threadIdx.x;
    int qbase = blockIdx.x * 32;        // 32 queries per block, all same batch
    int b = qbase >> 12;
    const float* xb = xyz + (size_t)b * NPTS * 3;
    for (int v = tid; v < NPTS * 3; v += 256) l_xyz[v] = xb[v];
    __syncthreads();

    int* idx_out   = (NS == SP) ? g_idx_p   : g_idx_d;
    int* empty_out = (NS == SP) ? g_empty_p : g_empty_d;

    int wave = tid >> 6, lane = tid & 63;
    for (int i = 0; i < 8; ++i) {
        int q = qbase + wave * 8 + i;
        float qx = newxyz[q * 3 + 0], qy = newxyz[q * 3 + 1], qz = newxyz[q * 3 + 2];
        float r = (NS == SP) ? RADIUS_C : g_rroi[q >> 6];
        float r2 = r * r;
        int cnt = 0, first_idx = 0;
        for (int g = 0; g < NPTS / 64 && cnt < NS; ++g) {
            int p = g * 64 + lane;
            float dx = qx - l_xyz[3 * p + 0];
            float dy = qy - l_xyz[3 * p + 1];
            float dz = qz - l_xyz[3 * p + 2];
            float d2 = dx * dx + dy * dy + dz * dz;
            bool valid = d2 < r2;
            unsigned long long mask = __ballot(valid);
            if (cnt == 0 && mask) first_idx = g * 64 + (int)__builtin_ctzll(mask);
            int pos = cnt + __popcll(mask & ((1ull << lane) - 1ull));
            if (valid && pos < NS) idx_out[q * NS + pos] = p;
            cnt += __popcll(mask);
        }
        if (cnt == 0) {
            if (lane < NS) idx_out[q * NS + lane] = 0;
            if (lane == 0) empty_out[q] = 1;
        } else {
            int filled = cnt < NS ? cnt : NS;
            if (lane >= filled && lane < NS) idx_out[q * NS + lane] = first_idx;
            if (lane == 0) empty_out[q] = 0;
        }
    }
}

// ---------------- p-branch layer 0: gather+group -> x0p, stats partials ----
__global__ void mlp_p0_kernel(const float* __restrict__ xyz, const float* __restrict__ feats,
                              const float* __restrict__ newxyz, const float* __restrict__ W) {
    __shared__ float l_in[8][36];
    __shared__ float l_red[256];
    int tid = threadIdx.x;
    int r = tid >> 5, ch = tid & 31;
    float wcol[35];
#pragma unroll
    for (int c = 0; c < 35; ++c) wcol[c] = W[c * CP + ch];
    float sum = 0.f, sq = 0.f;
    const int ITERS = (MTOT * SP) / (GRID_MLP * 8);   // 16
    for (int it = 0; it < ITERS; ++it) {
        int rowbase = (blockIdx.x * ITERS + it) * 8;
        for (int v = tid; v < 8 * 35; v += 256) {
            int rr = v / 35, c = v % 35;
            int row = rowbase + rr;
            int q = row >> 4;
            int bq = q >> 12;
            float val = 0.f;
            if (!g_empty_p[q]) {
                int idx = g_idx_p[row];
                if (c < 3) val = xyz[(size_t)bq * NPTS * 3 + idx * 3 + c] - newxyz[q * 3 + c];
                else       val = feats[(size_t)bq * NPTS * CIN + idx * CIN + (c - 3)];
            }
            l_in[rr][c] = val;
        }
        __syncthreads();
        float acc = 0.f;
#pragma unroll
        for (int c = 0; c < 35; ++c) acc += l_in[r][c] * wcol[c];
        g_x0p[(size_t)(rowbase + r) * CP + ch] = acc;
        sum += acc; sq += acc * acc;
        __syncthreads();
    }
    l_red[tid] = sum; __syncthreads();
    if (tid < CP) { float s = 0; for (int k = 0; k < 8; ++k) s += l_red[k * CP + tid]; g_ps[blockIdx.x * CP + tid] = s; }
    __syncthreads();
    l_red[tid] = sq; __syncthreads();
    if (tid < CP) { float s = 0; for (int k = 0; k < 8; ++k) s += l_red[k * CP + tid]; g_pq[blockIdx.x * CP + tid] = s; }
}

// ---------------- p-branch layer 1: BN+ReLU(x0p) @ pw1 -> x1p, stats -------
__global__ void mlp_p1_kernel(const float* __restrict__ W) {
    __shared__ float l_h[8][33];
    __shared__ float l_red[256];
    int tid = threadIdx.x;
    int r = tid >> 5, ch = tid & 31;
    float wcol[32];
#pragma unroll
    for (int c = 0; c < 32; ++c) wcol[c] = W[c * CP + ch];
    float sc = g_bnscale[0][ch], sh = g_bnshift[0][ch];
    float sum = 0.f, sq = 0.f;
    const int ITERS = (MTOT * SP) / (GRID_MLP * 8);
    for (int it = 0; it < ITERS; ++it) {
        int rowbase = (blockIdx.x * ITERS + it) * 8;
        float x = g_x0p[(size_t)(rowbase + r) * CP + ch];
        l_h[r][ch] = fmaxf(x * sc + sh, 0.f);
        __syncthreads();
        float acc = 0.f;
#pragma unroll
        for (int c = 0; c < 32; ++c) acc += l_h[r][c] * wcol[c];
        g_x1p[(size_t)(rowbase + r) * CP + ch] = acc;
        sum += acc; sq += acc * acc;
        __syncthreads();
    }
    l_red[tid] = sum; __syncthreads();
    if (tid < CP) { float s = 0; for (int k = 0; k < 8; ++k) s += l_red[k * CP + tid]; g_ps[blockIdx.x * CP + tid] = s; }
    __syncthreads();
    l_red[tid] = sq; __syncthreads();
    if (tid < CP) { float s = 0; for (int k = 0; k < 8; ++k) s += l_red[k * CP + tid]; g_pq[blockIdx.x * CP + tid] = s; }
}

// ---------------- f-branch layer 0 ----------------------------------------
__global__ void mlp_f0_kernel(const float* __restrict__ xyz, const float* __restrict__ feats,
                              const float* __restrict__ newxyz, const float* __restrict__ W) {
    __shared__ float l_in[4][36];
    __shared__ float l_red[256];
    int tid = threadIdx.x;
    int r = tid >> 6, ch = tid & 63;
    float wcol[35];
#pragma unroll
    for (int c = 0; c < 35; ++c) wcol[c] = W[c * CF + ch];
    float sum = 0.f, sq = 0.f;
    const int ITERS = (MTOT * SD) / (GRID_MLP * 4);   // 64
    for (int it = 0; it < ITERS; ++it) {
        int rowbase = (blockIdx.x * ITERS + it) * 4;
        if (tid < 4 * 35) {
            int rr = tid / 35, c = tid % 35;
            int row = rowbase + rr;
            int q = row >> 5;
            int bq = q >> 12;
            float val = 0.f;
            if (!g_empty_d[q]) {
                int idx = g_idx_d[row];
                if (c < 3) val = xyz[(size_t)bq * NPTS * 3 + idx * 3 + c] - newxyz[q * 3 + c];
                else       val = feats[(size_t)bq * NPTS * CIN + idx * CIN + (c - 3)];
            }
            l_in[rr][c] = val;
        }
        __syncthreads();
        float acc = 0.f;
#pragma unroll
        for (int c = 0; c < 35; ++c) acc += l_in[r][c] * wcol[c];
        g_x0f[(size_t)(rowbase + r) * CF + ch] = acc;
        sum += acc; sq += acc * acc;
        __syncthreads();
    }
    l_red[tid] = sum; __syncthreads();
    if (tid < CF) { float s = 0; for (int k = 0; k < 4; ++k) s += l_red[k * CF + tid]; g_ps[blockIdx.x * CF + tid] = s; }
    __syncthreads();
    l_red[tid] = sq; __syncthreads();
    if (tid < CF) { float s = 0; for (int k = 0; k < 4; ++k) s += l_red[k * CF + tid]; g_pq[blockIdx.x * CF + tid] = s; }
}

// ---------------- f-branch layer 1 ----------------------------------------
__global__ void mlp_f1_kernel(const float* __restrict__ W) {
    __shared__ float l_h[4][65];
    __shared__ float l_red[256];
    int tid = threadIdx.x;
    int r = tid >> 6, ch = tid & 63;
    float wcol[64];
#pragma unroll
    for (int c = 0; c < 64; ++c) wcol[c] = W[c * CF + ch];
    float sc = g_bnscale[2][ch], sh = g_bnshift[2][ch];
    float sum = 0.f, sq = 0.f;
    const int ITERS = (MTOT * SD) / (GRID_MLP * 4);
    for (int it = 0; it < ITERS; ++it) {
        int rowbase = (blockIdx.x * ITERS + it) * 4;
        float x = g_x0f[(size_t)(rowbase + r) * CF + ch];
        l_h[r][ch] = fmaxf(x * sc + sh, 0.f);
        __syncthreads();
        float acc = 0.f;
#pragma unroll
        for (int c = 0; c < 64; ++c) acc += l_h[r][c] * wcol[c];
        g_x1f[(size_t)(rowbase + r) * CF + ch] = acc;
        sum += acc; sq += acc * acc;
        __syncthreads();
    }
    l_red[tid] = sum; __syncthreads();
    if (tid < CF) { float s = 0; for (int k = 0; k < 4; ++k) s += l_red[k * CF + tid]; g_ps[blockIdx.x * CF + tid] = s; }
    __syncthreads();
    l_red[tid] = sq; __syncthreads();
    if (tid < CF) { float s = 0; for (int k = 0; k < 4; ++k) s += l_red[k * CF + tid]; g_pq[blockIdx.x * CF + tid] = s; }
}

// ---------------- BN stats finalize (deterministic, double accum) ----------
__global__ void finalize_kernel(const float* __restrict__ gamma, const float* __restrict__ beta,
                                int Cc, float n, int layer) {
    __shared__ double l_s[256], l_q[256];
    int tid = threadIdx.x;
    int nparts = 256 / Cc;
    int ch = tid % Cc, g = tid / Cc;
    double s = 0, q = 0;
    for (int i = g; i < GRID_MLP; i += nparts) { s += g_ps[i * Cc + ch]; q += g_pq[i * Cc + ch]; }
    l_s[tid] = s; l_q[tid] = q; __syncthreads();
    if (tid < Cc) {
        double S = 0, Q = 0;
        for (int k = 0; k < nparts; ++k) { S += l_s[k * Cc + tid]; Q += l_q[k * Cc + tid]; }
        double mu = S / (double)n;
        double var = Q / (double)n - mu * mu;
        if (var < 0) var = 0;
        double sc = (double)gamma[tid] / sqrt(var + 1e-5);
        g_bnscale[layer][tid] = (float)sc;
        g_bnshift[layer][tid] = (float)((double)beta[tid] - mu * sc);
    }
}

// ---------------- pooled max + per-query partial dot with fcw --------------
__global__ void pool_fc_kernel(const float* __restrict__ fcw) {
    int tid = threadIdx.x;
    int q = blockIdx.x * 8 + (tid >> 5);   // half-wave per query
    int ch = tid & 31;
    float sc = g_bnscale[1][ch], sh = g_bnshift[1][ch];
    float m = 0.f;
    for (int s = 0; s < SP; ++s) {
        float v = g_x1p[(size_t)(q * SP + s) * CP + ch] * sc + sh;
        m = fmaxf(m, fmaxf(v, 0.f));
    }
    float pd = m * fcw[(q & 63) * CP + ch];
    for (int off = 16; off > 0; off >>= 1) pd += __shfl_down(pd, off, 32);
    if (ch == 0) g_pdot[q] = pd;
}

// ---------------- per-roi fc reduce -> deform radius -----------------------
__global__ void roi_r_kernel(const float* __restrict__ roif, const float* __restrict__ fcw,
                             const float* __restrict__ fcb) {
    int tid = threadIdx.x;
    int roi = blockIdx.x * 4 + (tid >> 6);
    int lane = tid & 63;
    float acc = g_pdot[roi * 64 + lane]
              + roif[roi * 128 + lane]      * fcw[2048 + lane]
              + roif[roi * 128 + 64 + lane] * fcw[2048 + 64 + lane];
    for (int off = 32; off > 0; off >>= 1) acc += __shfl_down(acc, off, 64);
    if (lane == 0) {
        float res = acc + fcb[0];
        g_rroi[roi] = fmaxf(res / DIV_COEF_C + RADIUS_C, MIN_R_C);
    }
}

// ---------------- final: sigmoid weights * BN+ReLU(x1f), max over S --------
__global__ void final_kernel(const float* __restrict__ xyz, const float* __restrict__ newxyz,
                             const float* __restrict__ td, float* __restrict__ out) {
    __shared__ float l_w[SD];
    __shared__ float l_red[256];
    int tid = threadIdx.x;
    int ssub = tid >> 6, ch = tid & 63;
    float sc = g_bnscale[3][ch], sh = g_bnshift[3][ch];
    float temp = td[0];   // TEMPERATURE == 1.0
    for (int j = 0; j < 4; ++j) {
        int q = blockIdx.x * 4 + j;
        if (tid < SD) {
            int row = q * SD + tid;
            int idx = g_idx_d[row];
            int b = q >> 12;
            float dx = xyz[(size_t)b * NPTS * 3 + idx * 3 + 0] - newxyz[q * 3 + 0];
            float dy = xyz[(size_t)b * NPTS * 3 + idx * 3 + 1] - newxyz[q * 3 + 1];
            float dz = xyz[(size_t)b * NPTS * 3 + idx * 3 + 2] - newxyz[q * 3 + 2];
            float dist = sqrtf(dx * dx + dy * dy + dz * dz);
            float wv = 0.f;
            if (!g_empty_d[q]) {
                float rq = g_rroi[q >> 6];
                wv = 1.f / (1.f + expf(-(rq - dist) / temp));
            }
            l_w[tid] = wv;
        }
        __syncthreads();
        float m = 0.f;
#pragma unroll
        for (int k = 0; k < 8; ++k) {
            int s = ssub * 8 + k;
            float v = fmaxf(g_x1f[(size_t)(q * SD + s) * CF + ch] * sc + sh, 0.f);
            m = fmaxf(m, l_w[s] * v);
        }
        l_red[tid] = m; __syncthreads();
        if (tid < CF) {
            float mm = fmaxf(fmaxf(l_red[tid], l_red[64 + tid]),
                             fmaxf(l_red[128 + tid], l_red[192 + tid]));
            out[MTOT * 3 + (size_t)q * CF + tid] = mm;
        }
        __syncthreads();
    }
}

extern "C" void kernel_launch(void* const* d_in, const int* in_sizes, int n_in,
                              void* d_out, int out_size, void* d_ws, size_t ws_size,
                              hipStream_t stream) {
    const float* xyz   = (const float*)d_in[0];
    const float* feats = (const float*)d_in[1];
    const float* rois  = (const float*)d_in[2];   // == new_xyz flattened (8192,3)
    const float* roif  = (const float*)d_in[3];
    const float* td    = (const float*)d_in[4];
    const float* pw0 = (const float*)d_in[5];
    const float* pg0 = (const float*)d_in[6];
    const float* pb0 = (const float*)d_in[7];
    const float* pw1 = (const float*)d_in[8];
    const float* pg1 = (const float*)d_in[9];
    const float* pb1 = (const float*)d_in[10];
    const float* fw0 = (const float*)d_in[11];
    const float* fg0 = (const float*)d_in[12];
    const float* fb0 = (const float*)d_in[13];
    const float* fw1 = (const float*)d_in[14];
    const float* fg1 = (const float*)d_in[15];
    const float* fb1 = (const float*)d_in[16];
    const float* fcw = (const float*)d_in[17];
    const float* fcb = (const float*)d_in[18];
    float* out = (float*)d_out;

    copy_xyz_kernel<<<96, 256, 0, stream>>>(rois, out);

    // pred branch
    bq_kernel<SP><<<256, 256, 0, stream>>>(xyz, rois);
    mlp_p0_kernel<<<GRID_MLP, 256, 0, stream>>>(xyz, feats, rois, pw0);
    finalize_kernel<<<1, 256, 0, stream>>>(pg0, pb0, CP, (float)(MTOT * SP), 0);
    mlp_p1_kernel<<<GRID_MLP, 256, 0, stream>>>(pw1);
    finalize_kernel<<<1, 256, 0, stream>>>(pg1, pb1, CP, (float)(MTOT * SP), 1);
    pool_fc_kernel<<<MTOT / 8, 256, 0, stream>>>(fcw);
    roi_r_kernel<<<NROI / 4, 256, 0, stream>>>(roif, fcw, fcb);

    // deform branch
    bq_kernel<SD><<<256, 256, 0, stream>>>(xyz, rois);
    mlp_f0_kernel<<<GRID_MLP, 256, 0, stream>>>(xyz, feats, rois, fw0);
    finalize_kernel<<<1, 256, 0, stream>>>(fg0, fb0, CF, (float)(MTOT * SD), 2);
    mlp_f1_kernel<<<GRID_MLP, 256, 0, stream>>>(fw1);
    finalize_kernel<<<1, 256, 0, stream>>>(fg1, fb1, CF, (float)(MTOT * SD), 3);
    final_kernel<<<MTOT / 4, 256, 0, stream>>>(xyz, rois, td, out);
}

// Round 2
// 626.273 us; speedup vs baseline: 1.2059x; 1.2059x over previous
//
#include <hip/hip_runtime.h>

#define NB 2
#define NPTS 8192
#define NQ 4096
#define MTOT 8192      // NB*NQ
#define SP 16
#define SD 32
#define CIN 32
#define CP 32
#define CF 64
#define NROI 128       // NB*64
#define RADIUS_C 0.8f
#define MIN_R_C 0.01f
#define DIV_COEF_C 10.0f
#define GRID_MLP 1024

// ---------------- device-global scratch (fully rewritten every call) -------
__device__ int   g_idx_p[MTOT * SP];
__device__ int   g_empty_p[MTOT];
__device__ float g_x0p[MTOT * SP * CP];
__device__ float g_x1p[MTOT * SP * CP];
__device__ int   g_idx_d[MTOT * SD];
__device__ int   g_empty_d[MTOT];
__device__ float g_x0f[(size_t)MTOT * SD * CF];   // 64 MB
__device__ float g_x1f[(size_t)MTOT * SD * CF];   // 64 MB
__device__ float g_ps[GRID_MLP * CF];             // per-block channel sums
__device__ float g_pq[GRID_MLP * CF];             // per-block channel sumsq
__device__ float g_bnscale[4][CF];                // 0=p0 1=p1 2=f0 3=f1
__device__ float g_bnshift[4][CF];
__device__ float g_pdot[MTOT];
__device__ float g_rroi[NROI];

// ---------------- new_xyz output is rois flattened -------------------------
__global__ void copy_xyz_kernel(const float* __restrict__ rois, float* __restrict__ out) {
    int i = blockIdx.x * 256 + threadIdx.x;
    if (i < MTOT * 3) out[i] = rois[i];
}

// ---------------- ball query: one wave per query, index-ordered scan -------
// 1024-thread blocks: 16 waves share one 96KB LDS stage (4 waves/SIMD for
// latency hiding). Scan is software-pipelined: group g+1's LDS reads issue
// before group g's ballot chain.
template <int NS>
__launch_bounds__(1024, 4)
__global__ void bq_kernel(const float* __restrict__ xyz, const float* __restrict__ newxyz) {
    __shared__ float l_xyz[NPTS * 3];   // 96 KB
    int tid = threadIdx.x;
    int qbase = blockIdx.x * 32;        // 32 queries per block, all same batch
    int b = qbase >> 12;
    const float4* xb4 = (const float4*)(xyz + (size_t)b * NPTS * 3);
    float4* l4 = (float4*)l_xyz;
    for (int v = tid; v < NPTS * 3 / 4; v += 1024) l4[v] = xb4[v];
    __syncthreads();

    int* idx_out   = (NS == SP) ? g_idx_p   : g_idx_d;
    int* empty_out = (NS == SP) ? g_empty_p : g_empty_d;

    int wave = tid >> 6, lane = tid & 63;
    for (int i = 0; i < 2; ++i) {
        int q = qbase + wave * 2 + i;
        float qx = newxyz[q * 3 + 0], qy = newxyz[q * 3 + 1], qz = newxyz[q * 3 + 2];
        float r = (NS == SP) ? RADIUS_C : g_rroi[q >> 6];
        float r2 = r * r;
        int cnt = 0, first_idx = 0;
        // pipeline: cx/cy/cz hold group g's point, prefetch g+1 before chain
        float cx = l_xyz[3 * lane + 0];
        float cy = l_xyz[3 * lane + 1];
        float cz = l_xyz[3 * lane + 2];
        for (int g = 0; g < NPTS / 64 && cnt < NS; ++g) {
            int pn = (((g + 1) & 127) << 6) + lane;
            float nx = l_xyz[3 * pn + 0];
            float ny = l_xyz[3 * pn + 1];
            float nz = l_xyz[3 * pn + 2];
            float dx = qx - cx, dy = qy - cy, dz = qz - cz;
            float d2 = dx * dx + dy * dy + dz * dz;
            bool valid = d2 < r2;
            unsigned long long mask = __ballot(valid);
            if (cnt == 0 && mask) first_idx = (g << 6) + (int)__builtin_ctzll(mask);
            int pos = cnt + __popcll(mask & ((1ull << lane) - 1ull));
            if (valid && pos < NS) idx_out[q * NS + pos] = (g << 6) + lane;
            cnt += __popcll(mask);
            cx = nx; cy = ny; cz = nz;
        }
        if (cnt == 0) {
            if (lane < NS) idx_out[q * NS + lane] = 0;
            if (lane == 0) empty_out[q] = 1;
        } else {
            int filled = cnt < NS ? cnt : NS;
            if (lane >= filled && lane < NS) idx_out[q * NS + lane] = first_idx;
            if (lane == 0) empty_out[q] = 0;
        }
    }
}

// ---------------- p-branch layer 0: gather+group -> x0p, stats partials ----
__global__ void mlp_p0_kernel(const float* __restrict__ xyz, const float* __restrict__ feats,
                              const float* __restrict__ newxyz, const float* __restrict__ W) {
    __shared__ float l_in[8][36];
    __shared__ float l_red[256];
    int tid = threadIdx.x;
    int r = tid >> 5, ch = tid & 31;
    float wcol[35];
#pragma unroll
    for (int c = 0; c < 35; ++c) wcol[c] = W[c * CP + ch];
    float sum = 0.f, sq = 0.f;
    const int ITERS = (MTOT * SP) / (GRID_MLP * 8);   // 16
    for (int it = 0; it < ITERS; ++it) {
        int rowbase = (blockIdx.x * ITERS + it) * 8;
        for (int v = tid; v < 8 * 35; v += 256) {
            int rr = v / 35, c = v % 35;
            int row = rowbase + rr;
            int q = row >> 4;
            int bq = q >> 12;
            float val = 0.f;
            if (!g_empty_p[q]) {
                int idx = g_idx_p[row];
                if (c < 3) val = xyz[(size_t)bq * NPTS * 3 + idx * 3 + c] - newxyz[q * 3 + c];
                else       val = feats[(size_t)bq * NPTS * CIN + idx * CIN + (c - 3)];
            }
            l_in[rr][c] = val;
        }
        __syncthreads();
        float a0 = 0.f, a1 = 0.f;
#pragma unroll
        for (int c = 0; c < 34; c += 2) { a0 += l_in[r][c] * wcol[c]; a1 += l_in[r][c + 1] * wcol[c + 1]; }
        a0 += l_in[r][34] * wcol[34];
        float acc = a0 + a1;
        g_x0p[(size_t)(rowbase + r) * CP + ch] = acc;
        sum += acc; sq += acc * acc;
        __syncthreads();
    }
    l_red[tid] = sum; __syncthreads();
    if (tid < CP) { float s = 0; for (int k = 0; k < 8; ++k) s += l_red[k * CP + tid]; g_ps[blockIdx.x * CP + tid] = s; }
    __syncthreads();
    l_red[tid] = sq; __syncthreads();
    if (tid < CP) { float s = 0; for (int k = 0; k < 8; ++k) s += l_red[k * CP + tid]; g_pq[blockIdx.x * CP + tid] = s; }
}

// ---------------- p-branch layer 1: BN+ReLU(x0p) @ pw1 -> x1p, stats -------
__global__ void mlp_p1_kernel(const float* __restrict__ W) {
    __shared__ float l_h[8][33];
    __shared__ float l_red[256];
    int tid = threadIdx.x;
    int r = tid >> 5, ch = tid & 31;
    float wcol[32];
#pragma unroll
    for (int c = 0; c < 32; ++c) wcol[c] = W[c * CP + ch];
    float sc = g_bnscale[0][ch], sh = g_bnshift[0][ch];
    float sum = 0.f, sq = 0.f;
    const int ITERS = (MTOT * SP) / (GRID_MLP * 8);
    for (int it = 0; it < ITERS; ++it) {
        int rowbase = (blockIdx.x * ITERS + it) * 8;
        float x = g_x0p[(size_t)(rowbase + r) * CP + ch];
        l_h[r][ch] = fmaxf(x * sc + sh, 0.f);
        __syncthreads();
        float a0 = 0.f, a1 = 0.f;
#pragma unroll
        for (int c = 0; c < 32; c += 2) { a0 += l_h[r][c] * wcol[c]; a1 += l_h[r][c + 1] * wcol[c + 1]; }
        float acc = a0 + a1;
        g_x1p[(size_t)(rowbase + r) * CP + ch] = acc;
        sum += acc; sq += acc * acc;
        __syncthreads();
    }
    l_red[tid] = sum; __syncthreads();
    if (tid < CP) { float s = 0; for (int k = 0; k < 8; ++k) s += l_red[k * CP + tid]; g_ps[blockIdx.x * CP + tid] = s; }
    __syncthreads();
    l_red[tid] = sq; __syncthreads();
    if (tid < CP) { float s = 0; for (int k = 0; k < 8; ++k) s += l_red[k * CP + tid]; g_pq[blockIdx.x * CP + tid] = s; }
}

// ---------------- f-branch layer 0 ----------------------------------------
__global__ void mlp_f0_kernel(const float* __restrict__ xyz, const float* __restrict__ feats,
                              const float* __restrict__ newxyz, const float* __restrict__ W) {
    __shared__ float l_in[4][36];
    __shared__ float l_red[256];
    int tid = threadIdx.x;
    int r = tid >> 6, ch = tid & 63;
    float wcol[35];
#pragma unroll
    for (int c = 0; c < 35; ++c) wcol[c] = W[c * CF + ch];
    float sum = 0.f, sq = 0.f;
    const int ITERS = (MTOT * SD) / (GRID_MLP * 4);   // 64
    for (int it = 0; it < ITERS; ++it) {
        int rowbase = (blockIdx.x * ITERS + it) * 4;
        if (tid < 4 * 35) {
            int rr = tid / 35, c = tid % 35;
            int row = rowbase + rr;
            int q = row >> 5;
            int bq = q >> 12;
            float val = 0.f;
            if (!g_empty_d[q]) {
                int idx = g_idx_d[row];
                if (c < 3) val = xyz[(size_t)bq * NPTS * 3 + idx * 3 + c] - newxyz[q * 3 + c];
                else       val = feats[(size_t)bq * NPTS * CIN + idx * CIN + (c - 3)];
            }
            l_in[rr][c] = val;
        }
        __syncthreads();
        float a0 = 0.f, a1 = 0.f;
#pragma unroll
        for (int c = 0; c < 34; c += 2) { a0 += l_in[r][c] * wcol[c]; a1 += l_in[r][c + 1] * wcol[c + 1]; }
        a0 += l_in[r][34] * wcol[34];
        float acc = a0 + a1;
        g_x0f[(size_t)(rowbase + r) * CF + ch] = acc;
        sum += acc; sq += acc * acc;
        __syncthreads();
    }
    l_red[tid] = sum; __syncthreads();
    if (tid < CF) { float s = 0; for (int k = 0; k < 4; ++k) s += l_red[k * CF + tid]; g_ps[blockIdx.x * CF + tid] = s; }
    __syncthreads();
    l_red[tid] = sq; __syncthreads();
    if (tid < CF) { float s = 0; for (int k = 0; k < 4; ++k) s += l_red[k * CF + tid]; g_pq[blockIdx.x * CF + tid] = s; }
}

// ---------------- f-branch layer 1 ----------------------------------------
__global__ void mlp_f1_kernel(const float* __restrict__ W) {
    __shared__ float l_h[4][65];
    __shared__ float l_red[256];
    int tid = threadIdx.x;
    int r = tid >> 6, ch = tid & 63;
    float wcol[64];
#pragma unroll
    for (int c = 0; c < 64; ++c) wcol[c] = W[c * CF + ch];
    float sc = g_bnscale[2][ch], sh = g_bnshift[2][ch];
    float sum = 0.f, sq = 0.f;
    const int ITERS = (MTOT * SD) / (GRID_MLP * 4);
    for (int it = 0; it < ITERS; ++it) {
        int rowbase = (blockIdx.x * ITERS + it) * 4;
        float x = g_x0f[(size_t)(rowbase + r) * CF + ch];
        l_h[r][ch] = fmaxf(x * sc + sh, 0.f);
        __syncthreads();
        float a0 = 0.f, a1 = 0.f;
#pragma unroll
        for (int c = 0; c < 64; c += 2) { a0 += l_h[r][c] * wcol[c]; a1 += l_h[r][c + 1] * wcol[c + 1]; }
        float acc = a0 + a1;
        g_x1f[(size_t)(rowbase + r) * CF + ch] = acc;
        sum += acc; sq += acc * acc;
        __syncthreads();
    }
    l_red[tid] = sum; __syncthreads();
    if (tid < CF) { float s = 0; for (int k = 0; k < 4; ++k) s += l_red[k * CF + tid]; g_ps[blockIdx.x * CF + tid] = s; }
    __syncthreads();
    l_red[tid] = sq; __syncthreads();
    if (tid < CF) { float s = 0; for (int k = 0; k < 4; ++k) s += l_red[k * CF + tid]; g_pq[blockIdx.x * CF + tid] = s; }
}

// ---------------- BN stats finalize (deterministic, double accum) ----------
__global__ void finalize_kernel(const float* __restrict__ gamma, const float* __restrict__ beta,
                                int Cc, float n, int layer) {
    __shared__ double l_s[256], l_q[256];
    int tid = threadIdx.x;
    int nparts = 256 / Cc;
    int ch = tid % Cc, g = tid / Cc;
    double s = 0, q = 0;
    for (int i = g; i < GRID_MLP; i += nparts) { s += g_ps[i * Cc + ch]; q += g_pq[i * Cc + ch]; }
    l_s[tid] = s; l_q[tid] = q; __syncthreads();
    if (tid < Cc) {
        double S = 0, Q = 0;
        for (int k = 0; k < nparts; ++k) { S += l_s[k * Cc + tid]; Q += l_q[k * Cc + tid]; }
        double mu = S / (double)n;
        double var = Q / (double)n - mu * mu;
        if (var < 0) var = 0;
        double sc = (double)gamma[tid] / sqrt(var + 1e-5);
        g_bnscale[layer][tid] = (float)sc;
        g_bnshift[layer][tid] = (float)((double)beta[tid] - mu * sc);
    }
}

// ---------------- pooled max + per-query partial dot with fcw --------------
__global__ void pool_fc_kernel(const float* __restrict__ fcw) {
    int tid = threadIdx.x;
    int q = blockIdx.x * 8 + (tid >> 5);   // half-wave per query
    int ch = tid & 31;
    float sc = g_bnscale[1][ch], sh = g_bnshift[1][ch];
    float m = 0.f;
    for (int s = 0; s < SP; ++s) {
        float v = g_x1p[(size_t)(q * SP + s) * CP + ch] * sc + sh;
        m = fmaxf(m, fmaxf(v, 0.f));
    }
    float pd = m * fcw[(q & 63) * CP + ch];
    for (int off = 16; off > 0; off >>= 1) pd += __shfl_down(pd, off, 32);
    if (ch == 0) g_pdot[q] = pd;
}

// ---------------- per-roi fc reduce -> deform radius -----------------------
__global__ void roi_r_kernel(const float* __restrict__ roif, const float* __restrict__ fcw,
                             const float* __restrict__ fcb) {
    int tid = threadIdx.x;
    int roi = blockIdx.x * 4 + (tid >> 6);
    int lane = tid & 63;
    float acc = g_pdot[roi * 64 + lane]
              + roif[roi * 128 + lane]      * fcw[2048 + lane]
              + roif[roi * 128 + 64 + lane] * fcw[2048 + 64 + lane];
    for (int off = 32; off > 0; off >>= 1) acc += __shfl_down(acc, off, 64);
    if (lane == 0) {
        float res = acc + fcb[0];
        g_rroi[roi] = fmaxf(res / DIV_COEF_C + RADIUS_C, MIN_R_C);
    }
}

// ---------------- final: sigmoid weights * BN+ReLU(x1f), max over S --------
__global__ void final_kernel(const float* __restrict__ xyz, const float* __restrict__ newxyz,
                             const float* __restrict__ td, float* __restrict__ out) {
    __shared__ float l_w[SD];
    __shared__ float l_red[256];
    int tid = threadIdx.x;
    int ssub = tid >> 6, ch = tid & 63;
    float sc = g_bnscale[3][ch], sh = g_bnshift[3][ch];
    float temp = td[0];   // TEMPERATURE == 1.0
    for (int j = 0; j < 4; ++j) {
        int q = blockIdx.x * 4 + j;
        if (tid < SD) {
            int row = q * SD + tid;
            int idx = g_idx_d[row];
            int b = q >> 12;
            float dx = xyz[(size_t)b * NPTS * 3 + idx * 3 + 0] - newxyz[q * 3 + 0];
            float dy = xyz[(size_t)b * NPTS * 3 + idx * 3 + 1] - newxyz[q * 3 + 1];
            float dz = xyz[(size_t)b * NPTS * 3 + idx * 3 + 2] - newxyz[q * 3 + 2];
            float dist = sqrtf(dx * dx + dy * dy + dz * dz);
            float wv = 0.f;
            if (!g_empty_d[q]) {
                float rq = g_rroi[q >> 6];
                wv = 1.f / (1.f + expf(-(rq - dist) / temp));
            }
            l_w[tid] = wv;
        }
        __syncthreads();
        float m = 0.f;
#pragma unroll
        for (int k = 0; k < 8; ++k) {
            int s = ssub * 8 + k;
            float v = fmaxf(g_x1f[(size_t)(q * SD + s) * CF + ch] * sc + sh, 0.f);
            m = fmaxf(m, l_w[s] * v);
        }
        l_red[tid] = m; __syncthreads();
        if (tid < CF) {
            float mm = fmaxf(fmaxf(l_red[tid], l_red[64 + tid]),
                             fmaxf(l_red[128 + tid], l_red[192 + tid]));
            out[MTOT * 3 + (size_t)q * CF + tid] = mm;
        }
        __syncthreads();
    }
}

extern "C" void kernel_launch(void* const* d_in, const int* in_sizes, int n_in,
                              void* d_out, int out_size, void* d_ws, size_t ws_size,
                              hipStream_t stream) {
    const float* xyz   = (const float*)d_in[0];
    const float* feats = (const float*)d_in[1];
    const float* rois  = (const float*)d_in[2];   // == new_xyz flattened (8192,3)
    const float* roif  = (const float*)d_in[3];
    const float* td    = (const float*)d_in[4];
    const float* pw0 = (const float*)d_in[5];
    const float* pg0 = (const float*)d_in[6];
    const float* pb0 = (const float*)d_in[7];
    const float* pw1 = (const float*)d_in[8];
    const float* pg1 = (const float*)d_in[9];
    const float* pb1 = (const float*)d_in[10];
    const float* fw0 = (const float*)d_in[11];
    const float* fg0 = (const float*)d_in[12];
    const float* fb0 = (const float*)d_in[13];
    const float* fw1 = (const float*)d_in[14];
    const float* fg1 = (const float*)d_in[15];
    const float* fb1 = (const float*)d_in[16];
    const float* fcw = (const float*)d_in[17];
    const float* fcb = (const float*)d_in[18];
    float* out = (float*)d_out;

    copy_xyz_kernel<<<96, 256, 0, stream>>>(rois, out);

    // pred branch
    bq_kernel<SP><<<256, 1024, 0, stream>>>(xyz, rois);
    mlp_p0_kernel<<<GRID_MLP, 256, 0, stream>>>(xyz, feats, rois, pw0);
    finalize_kernel<<<1, 256, 0, stream>>>(pg0, pb0, CP, (float)(MTOT * SP), 0);
    mlp_p1_kernel<<<GRID_MLP, 256, 0, stream>>>(pw1);
    finalize_kernel<<<1, 256, 0, stream>>>(pg1, pb1, CP, (float)(MTOT * SP), 1);
    pool_fc_kernel<<<MTOT / 8, 256, 0, stream>>>(fcw);
    roi_r_kernel<<<NROI / 4, 256, 0, stream>>>(roif, fcw, fcb);

    // deform branch
    bq_kernel<SD><<<256, 1024, 0, stream>>>(xyz, rois);
    mlp_f0_kernel<<<GRID_MLP, 256, 0, stream>>>(xyz, feats, rois, fw0);
    finalize_kernel<<<1, 256, 0, stream>>>(fg0, fb0, CF, (float)(MTOT * SD), 2);
    mlp_f1_kernel<<<GRID_MLP, 256, 0, stream>>>(fw1);
    finalize_kernel<<<1, 256, 0, stream>>>(fg1, fb1, CF, (float)(MTOT * SD), 3);
    final_kernel<<<MTOT / 4, 256, 0, stream>>>(xyz, rois, td, out);
}

// Round 3
// 524.570 us; speedup vs baseline: 1.4397x; 1.1939x over previous
//
#include <hip/hip_runtime.h>

#define NB 2
#define NPTS 8192
#define NQ 4096
#define MTOT 8192      // NB*NQ
#define SP 16
#define SD 32
#define CIN 32
#define CP 32
#define CF 64
#define NROI 128       // NB*64
#define RADIUS_C 0.8f
#define MIN_R_C 0.01f
#define DIV_COEF_C 10.0f

// ---------------- device-global scratch (fully rewritten every call) -------
__device__ int   g_idx_p[MTOT * SP];
__device__ int   g_empty_p[MTOT];
__device__ float g_x0p[MTOT * SP * CP];
__device__ float g_x1p[MTOT * SP * CP];
__device__ int   g_idx_d[MTOT * SD];
__device__ int   g_empty_d[MTOT];
__device__ float g_x0f[(size_t)MTOT * SD * CF];   // 64 MB
__device__ float g_x1f[(size_t)MTOT * SD * CF];   // 64 MB
__device__ float g_ps[1024 * CF];                 // per-block channel sums
__device__ float g_pq[1024 * CF];                 // per-block channel sumsq
__device__ float g_bnscale[4][CF];                // 0=p0 1=p1 2=f0 3=f1
__device__ float g_bnshift[4][CF];
__device__ float g_pdot[MTOT];
__device__ float g_rroi[NROI];

// ---------------- new_xyz output is rois flattened -------------------------
__global__ void copy_xyz_kernel(const float* __restrict__ rois, float* __restrict__ out) {
    int i = blockIdx.x * 256 + threadIdx.x;
    if (i < MTOT * 3) out[i] = rois[i];
}

// ---------------- ball query: one wave per query, index-ordered scan -------
template <int NS>
__launch_bounds__(1024, 4)
__global__ void bq_kernel(const float* __restrict__ xyz, const float* __restrict__ newxyz) {
    __shared__ float l_xyz[NPTS * 3];   // 96 KB
    int tid = threadIdx.x;
    int qbase = blockIdx.x * 32;        // 32 queries per block, all same batch
    int b = qbase >> 12;
    const float4* xb4 = (const float4*)(xyz + (size_t)b * NPTS * 3);
    float4* l4 = (float4*)l_xyz;
    for (int v = tid; v < NPTS * 3 / 4; v += 1024) l4[v] = xb4[v];
    __syncthreads();

    int* idx_out   = (NS == SP) ? g_idx_p   : g_idx_d;
    int* empty_out = (NS == SP) ? g_empty_p : g_empty_d;

    int wave = tid >> 6, lane = tid & 63;
    for (int i = 0; i < 2; ++i) {
        int q = qbase + wave * 2 + i;
        float qx = newxyz[q * 3 + 0], qy = newxyz[q * 3 + 1], qz = newxyz[q * 3 + 2];
        float r = (NS == SP) ? RADIUS_C : g_rroi[q >> 6];
        float r2 = r * r;
        int cnt = 0, first_idx = 0;
        float cx = l_xyz[3 * lane + 0];
        float cy = l_xyz[3 * lane + 1];
        float cz = l_xyz[3 * lane + 2];
        for (int g = 0; g < NPTS / 64 && cnt < NS; ++g) {
            int pn = (((g + 1) & 127) << 6) + lane;
            float nx = l_xyz[3 * pn + 0];
            float ny = l_xyz[3 * pn + 1];
            float nz = l_xyz[3 * pn + 2];
            float dx = qx - cx, dy = qy - cy, dz = qz - cz;
            float d2 = dx * dx + dy * dy + dz * dz;
            bool valid = d2 < r2;
            unsigned long long mask = __ballot(valid);
            if (cnt == 0 && mask) first_idx = (g << 6) + (int)__builtin_ctzll(mask);
            int pos = cnt + __popcll(mask & ((1ull << lane) - 1ull));
            if (valid && pos < NS) idx_out[q * NS + pos] = (g << 6) + lane;
            cnt += __popcll(mask);
            cx = nx; cy = ny; cz = nz;
        }
        if (cnt == 0) {
            if (lane < NS) idx_out[q * NS + lane] = 0;
            if (lane == 0) empty_out[q] = 1;
        } else {
            int filled = cnt < NS ? cnt : NS;
            if (lane >= filled && lane < NS) idx_out[q * NS + lane] = first_idx;
            if (lane == 0) empty_out[q] = 0;
        }
    }
}

// ============ register-tiled MLP layers: lane=row, acc[ch] in VGPRs, =======
// ============ W[c][ch] as wave-uniform s_load operand, ~no barriers  =======

// f-branch layer 0: gather (idx_d) -> 35x64 matmul -> x0f + stats partials
__global__ void mlp_f0_kernel(const float* __restrict__ xyz, const float* __restrict__ feats,
                              const float* __restrict__ newxyz, const float* __restrict__ W) {
    __shared__ float buf[256 * 65];   // in-tile pad 37 / out-tile pad 65 (66.6 KB)
    __shared__ float ls[256], lq[256];
    int tid = threadIdx.x;
    int rowbase = blockIdx.x * 256;
    // stage: thread t stages row rowbase+t into buf[t*37 .. +34]
    {
        int row = rowbase + tid;
        int q = row >> 5, b = q >> 12;
        float* dst = &buf[tid * 37];
        if (g_empty_d[q]) {
#pragma unroll
            for (int c = 0; c < 35; ++c) dst[c] = 0.f;
        } else {
            int idx = g_idx_d[row];
            const float* xp = xyz + (size_t)b * NPTS * 3 + idx * 3;
            dst[0] = xp[0] - newxyz[q * 3 + 0];
            dst[1] = xp[1] - newxyz[q * 3 + 1];
            dst[2] = xp[2] - newxyz[q * 3 + 2];
            const float4* fp = (const float4*)(feats + (size_t)b * NPTS * CIN + (size_t)idx * CIN);
#pragma unroll
            for (int j = 0; j < 8; ++j) {
                float4 v = fp[j];
                dst[3 + 4 * j + 0] = v.x; dst[3 + 4 * j + 1] = v.y;
                dst[3 + 4 * j + 2] = v.z; dst[3 + 4 * j + 3] = v.w;
            }
        }
    }
    // compute reads same-thread's row -> no barrier needed before compute
    int w = tid >> 6, lane = tid & 63;
    const float* inrow = &buf[tid * 37];
    float acc[64];
#pragma unroll
    for (int ch = 0; ch < 64; ++ch) acc[ch] = 0.f;
    for (int c = 0; c < 35; ++c) {
        float h = inrow[c];
#pragma unroll
        for (int ch = 0; ch < 64; ++ch) acc[ch] = fmaf(h, W[c * 64 + ch], acc[ch]);
    }
    __syncthreads();   // out-tile (pad 65) overlaps other waves' in-tile rows
    float* orow = &buf[tid * 65];
#pragma unroll
    for (int ch = 0; ch < 64; ++ch) orow[ch] = acc[ch];
    // wave-synchronous LDS transpose: lane=ch, coalesced store + stats
    float sum = 0.f, sq = 0.f;
    for (int r = 0; r < 64; ++r) {
        float v = buf[(w * 64 + r) * 65 + lane];
        g_x0f[(size_t)(rowbase + w * 64 + r) * 64 + lane] = v;
        sum += v; sq += v * v;
    }
    ls[tid] = sum; lq[tid] = sq; __syncthreads();
    if (tid < 64) {
        g_ps[blockIdx.x * 64 + tid] = ls[tid] + ls[64 + tid] + ls[128 + tid] + ls[192 + tid];
        g_pq[blockIdx.x * 64 + tid] = lq[tid] + lq[64 + tid] + lq[128 + tid] + lq[192 + tid];
    }
}

// f-branch layer 1: BN+ReLU(x0f) -> 64x64 matmul -> x1f + stats partials
__global__ void mlp_f1_kernel(const float* __restrict__ W) {
    __shared__ float buf[256 * 65];
    __shared__ float ls[256], lq[256];
    int tid = threadIdx.x;
    int rowbase = blockIdx.x * 256;
    const float4* src = (const float4*)g_x0f;
#pragma unroll
    for (int k = 0; k < 16; ++k) {
        int o4 = tid + k * 256;
        float4 v = src[(size_t)rowbase * 16 + o4];
        int o = o4 * 4, row = o >> 6, c = o & 63;
        float* d = &buf[row * 65 + c];
        d[0] = v.x; d[1] = v.y; d[2] = v.z; d[3] = v.w;
    }
    __syncthreads();
    int w = tid >> 6, lane = tid & 63;
    const float* inrow = &buf[tid * 65];
    float acc[64];
#pragma unroll
    for (int ch = 0; ch < 64; ++ch) acc[ch] = 0.f;
    for (int c = 0; c < 64; ++c) {
        float h = fmaxf(fmaf(inrow[c], g_bnscale[2][c], g_bnshift[2][c]), 0.f);
#pragma unroll
        for (int ch = 0; ch < 64; ++ch) acc[ch] = fmaf(h, W[c * 64 + ch], acc[ch]);
    }
    // in/out tiles share pad 65 and rows are wave-private -> no barrier
    float* orow = &buf[tid * 65];
#pragma unroll
    for (int ch = 0; ch < 64; ++ch) orow[ch] = acc[ch];
    float sum = 0.f, sq = 0.f;
    for (int r = 0; r < 64; ++r) {
        float v = buf[(w * 64 + r) * 65 + lane];
        g_x1f[(size_t)(rowbase + w * 64 + r) * 64 + lane] = v;
        sum += v; sq += v * v;
    }
    ls[tid] = sum; lq[tid] = sq; __syncthreads();
    if (tid < 64) {
        g_ps[blockIdx.x * 64 + tid] = ls[tid] + ls[64 + tid] + ls[128 + tid] + ls[192 + tid];
        g_pq[blockIdx.x * 64 + tid] = lq[tid] + lq[64 + tid] + lq[128 + tid] + lq[192 + tid];
    }
}

// p-branch layer 0: gather (idx_p) -> 35x32 matmul -> x0p + stats partials
__global__ void mlp_p0_kernel(const float* __restrict__ xyz, const float* __restrict__ feats,
                              const float* __restrict__ newxyz, const float* __restrict__ W) {
    __shared__ float buf[256 * 37];
    __shared__ float ls[256], lq[256];
    int tid = threadIdx.x;
    int rowbase = blockIdx.x * 256;
    {
        int row = rowbase + tid;
        int q = row >> 4, b = q >> 12;
        float* dst = &buf[tid * 37];
        if (g_empty_p[q]) {
#pragma unroll
            for (int c = 0; c < 35; ++c) dst[c] = 0.f;
        } else {
            int idx = g_idx_p[row];
            const float* xp = xyz + (size_t)b * NPTS * 3 + idx * 3;
            dst[0] = xp[0] - newxyz[q * 3 + 0];
            dst[1] = xp[1] - newxyz[q * 3 + 1];
            dst[2] = xp[2] - newxyz[q * 3 + 2];
            const float4* fp = (const float4*)(feats + (size_t)b * NPTS * CIN + (size_t)idx * CIN);
#pragma unroll
            for (int j = 0; j < 8; ++j) {
                float4 v = fp[j];
                dst[3 + 4 * j + 0] = v.x; dst[3 + 4 * j + 1] = v.y;
                dst[3 + 4 * j + 2] = v.z; dst[3 + 4 * j + 3] = v.w;
            }
        }
    }
    int w = tid >> 6, lane = tid & 63;
    const float* inrow = &buf[tid * 37];
    float acc[32];
#pragma unroll
    for (int ch = 0; ch < 32; ++ch) acc[ch] = 0.f;
    for (int c = 0; c < 35; ++c) {
        float h = inrow[c];
#pragma unroll
        for (int ch = 0; ch < 32; ++ch) acc[ch] = fmaf(h, W[c * 32 + ch], acc[ch]);
    }
    __syncthreads();   // out-tile pad 33 overlaps other waves' in-tile rows
    float* orow = &buf[tid * 33];
#pragma unroll
    for (int ch = 0; ch < 32; ++ch) orow[ch] = acc[ch];
    float sum = 0.f, sq = 0.f;
    int rh = lane >> 5, cl = lane & 31;   // 2 rows per iteration
    for (int r = 0; r < 32; ++r) {
        float v = buf[(w * 64 + r * 2 + rh) * 33 + cl];
        g_x0p[(size_t)(rowbase + w * 64 + r * 2) * 32 + lane] = v;
        sum += v; sq += v * v;
    }
    ls[tid] = sum; lq[tid] = sq; __syncthreads();
    if (tid < 32) {
        float s = 0.f, qq = 0.f;
#pragma unroll
        for (int k = 0; k < 8; ++k) { s += ls[tid + 32 * k]; qq += lq[tid + 32 * k]; }
        g_ps[blockIdx.x * 32 + tid] = s;
        g_pq[blockIdx.x * 32 + tid] = qq;
    }
}

// p-branch layer 1: BN+ReLU(x0p) -> 32x32 matmul -> x1p + stats partials
__global__ void mlp_p1_kernel(const float* __restrict__ W) {
    __shared__ float buf[256 * 33];
    __shared__ float ls[256], lq[256];
    int tid = threadIdx.x;
    int rowbase = blockIdx.x * 256;
    const float4* src = (const float4*)g_x0p;
#pragma unroll
    for (int k = 0; k < 8; ++k) {
        int o4 = tid + k * 256;
        float4 v = src[(size_t)rowbase * 8 + o4];
        int o = o4 * 4, row = o >> 5, c = o & 31;
        float* d = &buf[row * 33 + c];
        d[0] = v.x; d[1] = v.y; d[2] = v.z; d[3] = v.w;
    }
    __syncthreads();
    int w = tid >> 6, lane = tid & 63;
    const float* inrow = &buf[tid * 33];
    float acc[32];
#pragma unroll
    for (int ch = 0; ch < 32; ++ch) acc[ch] = 0.f;
    for (int c = 0; c < 32; ++c) {
        float h = fmaxf(fmaf(inrow[c], g_bnscale[0][c], g_bnshift[0][c]), 0.f);
#pragma unroll
        for (int ch = 0; ch < 32; ++ch) acc[ch] = fmaf(h, W[c * 32 + ch], acc[ch]);
    }
    float* orow = &buf[tid * 33];   // same pad, wave-private rows -> no barrier
#pragma unroll
    for (int ch = 0; ch < 32; ++ch) orow[ch] = acc[ch];
    float sum = 0.f, sq = 0.f;
    int rh = lane >> 5, cl = lane & 31;
    for (int r = 0; r < 32; ++r) {
        float v = buf[(w * 64 + r * 2 + rh) * 33 + cl];
        g_x1p[(size_t)(rowbase + w * 64 + r * 2) * 32 + lane] = v;
        sum += v; sq += v * v;
    }
    ls[tid] = sum; lq[tid] = sq; __syncthreads();
    if (tid < 32) {
        float s = 0.f, qq = 0.f;
#pragma unroll
        for (int k = 0; k < 8; ++k) { s += ls[tid + 32 * k]; qq += lq[tid + 32 * k]; }
        g_ps[blockIdx.x * 32 + tid] = s;
        g_pq[blockIdx.x * 32 + tid] = qq;
    }
}

// ---------------- BN stats finalize (deterministic, double accum) ----------
__global__ void finalize_kernel(const float* __restrict__ gamma, const float* __restrict__ beta,
                                int Cc, float n, int layer, int nblocks) {
    __shared__ double l_s[256], l_q[256];
    int tid = threadIdx.x;
    int nparts = 256 / Cc;
    int ch = tid % Cc, g = tid / Cc;
    double s = 0, q = 0;
    for (int i = g; i < nblocks; i += nparts) { s += g_ps[i * Cc + ch]; q += g_pq[i * Cc + ch]; }
    l_s[tid] = s; l_q[tid] = q; __syncthreads();
    if (tid < Cc) {
        double S = 0, Q = 0;
        for (int k = 0; k < nparts; ++k) { S += l_s[k * Cc + tid]; Q += l_q[k * Cc + tid]; }
        double mu = S / (double)n;
        double var = Q / (double)n - mu * mu;
        if (var < 0) var = 0;
        double sc = (double)gamma[tid] / sqrt(var + 1e-5);
        g_bnscale[layer][tid] = (float)sc;
        g_bnshift[layer][tid] = (float)((double)beta[tid] - mu * sc);
    }
}

// ---------------- pooled max + per-query partial dot with fcw --------------
__global__ void pool_fc_kernel(const float* __restrict__ fcw) {
    int tid = threadIdx.x;
    int q = blockIdx.x * 8 + (tid >> 5);
    int ch = tid & 31;
    float sc = g_bnscale[1][ch], sh = g_bnshift[1][ch];
    float m = 0.f;
    for (int s = 0; s < SP; ++s) {
        float v = g_x1p[(size_t)(q * SP + s) * CP + ch] * sc + sh;
        m = fmaxf(m, fmaxf(v, 0.f));
    }
    float pd = m * fcw[(q & 63) * CP + ch];
    for (int off = 16; off > 0; off >>= 1) pd += __shfl_down(pd, off, 32);
    if (ch == 0) g_pdot[q] = pd;
}

// ---------------- per-roi fc reduce -> deform radius -----------------------
__global__ void roi_r_kernel(const float* __restrict__ roif, const float* __restrict__ fcw,
                             const float* __restrict__ fcb) {
    int tid = threadIdx.x;
    int roi = blockIdx.x * 4 + (tid >> 6);
    int lane = tid & 63;
    float acc = g_pdot[roi * 64 + lane]
              + roif[roi * 128 + lane]      * fcw[2048 + lane]
              + roif[roi * 128 + 64 + lane] * fcw[2048 + 64 + lane];
    for (int off = 32; off > 0; off >>= 1) acc += __shfl_down(acc, off, 64);
    if (lane == 0) {
        float res = acc + fcb[0];
        g_rroi[roi] = fmaxf(res / DIV_COEF_C + RADIUS_C, MIN_R_C);
    }
}

// ---------------- final: sigmoid weights * BN+ReLU(x1f), max over S --------
__global__ void final_kernel(const float* __restrict__ xyz, const float* __restrict__ newxyz,
                             const float* __restrict__ td, float* __restrict__ out) {
    __shared__ float  lw[2][32];
    __shared__ float4 lp[2][8][16];
    int tid = threadIdx.x;
    int qpair = blockIdx.x * 2;
    float temp = td[0];
    if (tid < 64) {
        int ql = tid >> 5, s = tid & 31;
        int q = qpair + ql;
        float wv = 0.f;
        if (!g_empty_d[q]) {
            int idx = g_idx_d[q * SD + s];
            int b = q >> 12;
            float dx = xyz[(size_t)b * NPTS * 3 + idx * 3 + 0] - newxyz[q * 3 + 0];
            float dy = xyz[(size_t)b * NPTS * 3 + idx * 3 + 1] - newxyz[q * 3 + 1];
            float dz = xyz[(size_t)b * NPTS * 3 + idx * 3 + 2] - newxyz[q * 3 + 2];
            float dist = sqrtf(dx * dx + dy * dy + dz * dz);
            float rq = g_rroi[q >> 6];
            wv = 1.f / (1.f + expf(-(rq - dist) / temp));
        }
        lw[ql][s] = wv;
    }
    __syncthreads();
    {
        int ql = tid >> 7, u = tid & 127;
        int ch4 = u & 15, sg = u >> 4;
        int q = qpair + ql;
        const float4* x4 = (const float4*)g_x1f;
        const float4* sc4 = (const float4*)g_bnscale[3];
        const float4* sh4 = (const float4*)g_bnshift[3];
        float4 SC = sc4[ch4], SH = sh4[ch4];
        float4 m = make_float4(0.f, 0.f, 0.f, 0.f);
#pragma unroll
        for (int k = 0; k < 4; ++k) {
            int s = sg * 4 + k;
            float4 x = x4[((size_t)q * SD + s) * 16 + ch4];
            float ws = lw[ql][s];
            m.x = fmaxf(m.x, ws * fmaxf(fmaf(x.x, SC.x, SH.x), 0.f));
            m.y = fmaxf(m.y, ws * fmaxf(fmaf(x.y, SC.y, SH.y), 0.f));
            m.z = fmaxf(m.z, ws * fmaxf(fmaf(x.z, SC.z, SH.z), 0.f));
            m.w = fmaxf(m.w, ws * fmaxf(fmaf(x.w, SC.w, SH.w), 0.f));
        }
        lp[ql][sg][ch4] = m;
    }
    __syncthreads();
    if (tid < 128) {
        int ql = tid >> 6, ch = tid & 63;
        const float* base = (const float*)&lp[ql][0][0];
        float mm = 0.f;
#pragma unroll
        for (int sg = 0; sg < 8; ++sg) mm = fmaxf(mm, base[sg * 64 + ch]);
        out[MTOT * 3 + (size_t)(qpair + ql) * CF + ch] = mm;
    }
}

extern "C" void kernel_launch(void* const* d_in, const int* in_sizes, int n_in,
                              void* d_out, int out_size, void* d_ws, size_t ws_size,
                              hipStream_t stream) {
    const float* xyz   = (const float*)d_in[0];
    const float* feats = (const float*)d_in[1];
    const float* rois  = (const float*)d_in[2];
    const float* roif  = (const float*)d_in[3];
    const float* td    = (const float*)d_in[4];
    const float* pw0 = (const float*)d_in[5];
    const float* pg0 = (const float*)d_in[6];
    const float* pb0 = (const float*)d_in[7];
    const float* pw1 = (const float*)d_in[8];
    const float* pg1 = (const float*)d_in[9];
    const float* pb1 = (const float*)d_in[10];
    const float* fw0 = (const float*)d_in[11];
    const float* fg0 = (const float*)d_in[12];
    const float* fb0 = (const float*)d_in[13];
    const float* fw1 = (const float*)d_in[14];
    const float* fg1 = (const float*)d_in[15];
    const float* fb1 = (const float*)d_in[16];
    const float* fcw = (const float*)d_in[17];
    const float* fcb = (const float*)d_in[18];
    float* out = (float*)d_out;

    copy_xyz_kernel<<<96, 256, 0, stream>>>(rois, out);

    // pred branch
    bq_kernel<SP><<<256, 1024, 0, stream>>>(xyz, rois);
    mlp_p0_kernel<<<512, 256, 0, stream>>>(xyz, feats, rois, pw0);
    finalize_kernel<<<1, 256, 0, stream>>>(pg0, pb0, CP, (float)(MTOT * SP), 0, 512);
    mlp_p1_kernel<<<512, 256, 0, stream>>>(pw1);
    finalize_kernel<<<1, 256, 0, stream>>>(pg1, pb1, CP, (float)(MTOT * SP), 1, 512);
    pool_fc_kernel<<<MTOT / 8, 256, 0, stream>>>(fcw);
    roi_r_kernel<<<NROI / 4, 256, 0, stream>>>(roif, fcw, fcb);

    // deform branch
    bq_kernel<SD><<<256, 1024, 0, stream>>>(xyz, rois);
    mlp_f0_kernel<<<1024, 256, 0, stream>>>(xyz, feats, rois, fw0);
    finalize_kernel<<<1, 256, 0, stream>>>(fg0, fb0, CF, (float)(MTOT * SD), 2, 1024);
    mlp_f1_kernel<<<1024, 256, 0, stream>>>(fw1);
    finalize_kernel<<<1, 256, 0, stream>>>(fg1, fb1, CF, (float)(MTOT * SD), 3, 1024);
    final_kernel<<<MTOT / 2, 256, 0, stream>>>(xyz, rois, td, out);
}

// Round 4
// 347.087 us; speedup vs baseline: 2.1759x; 1.5113x over previous
//
#include <hip/hip_runtime.h>

#define NB 2
#define NPTS 8192
#define NQ 4096
#define MTOT 8192      // NB*NQ
#define SP 16
#define SD 32
#define CIN 32
#define CP 32
#define CF 64
#define NROI 128       // NB*64
#define RADIUS_C 0.8f
#define MIN_R_C 0.01f
#define DIV_COEF_C 10.0f

// ---------------- device-global scratch (fully rewritten every call) -------
__device__ int   g_idx_p[MTOT * SP];
__device__ int   g_empty_p[MTOT];
__device__ float g_x0p[MTOT * SP * CP];
__device__ float g_x1p[MTOT * SP * CP];
__device__ int   g_idx_d[MTOT * SD];
__device__ int   g_empty_d[MTOT];
__device__ float g_x0f[(size_t)MTOT * SD * CF];   // 64 MB
__device__ float g_x1f[(size_t)MTOT * SD * CF];   // 64 MB
__device__ float g_psT[CF * 1024];                // transposed: [ch][block]
__device__ float g_pqT[CF * 1024];
__device__ float g_bnscale[4][CF];                // 0=p0 1=p1 2=f0 3=f1
__device__ float g_bnshift[4][CF];
__device__ float g_pdot[MTOT];
__device__ float g_rroi[NROI];

// ---------------- new_xyz output is rois flattened -------------------------
__global__ void copy_xyz_kernel(const float* __restrict__ rois, float* __restrict__ out) {
    int i = blockIdx.x * 256 + threadIdx.x;
    if (i < MTOT * 3) out[i] = rois[i];
}

// ---------------- ball query: one wave per query, index-ordered scan -------
template <int NS>
__launch_bounds__(1024, 4)
__global__ void bq_kernel(const float* __restrict__ xyz, const float* __restrict__ newxyz) {
    __shared__ float l_xyz[NPTS * 3];   // 96 KB
    int tid = threadIdx.x;
    int qbase = blockIdx.x * 32;        // 32 queries per block, all same batch
    int b = qbase >> 12;
    const float4* xb4 = (const float4*)(xyz + (size_t)b * NPTS * 3);
    float4* l4 = (float4*)l_xyz;
    for (int v = tid; v < NPTS * 3 / 4; v += 1024) l4[v] = xb4[v];
    __syncthreads();

    int* idx_out   = (NS == SP) ? g_idx_p   : g_idx_d;
    int* empty_out = (NS == SP) ? g_empty_p : g_empty_d;

    int wave = tid >> 6, lane = tid & 63;
    for (int i = 0; i < 2; ++i) {
        int q = qbase + wave * 2 + i;
        float qx = newxyz[q * 3 + 0], qy = newxyz[q * 3 + 1], qz = newxyz[q * 3 + 2];
        float r = (NS == SP) ? RADIUS_C : g_rroi[q >> 6];
        float r2 = r * r;
        int cnt = 0, first_idx = 0;
        float cx = l_xyz[3 * lane + 0];
        float cy = l_xyz[3 * lane + 1];
        float cz = l_xyz[3 * lane + 2];
        for (int g = 0; g < NPTS / 64 && cnt < NS; ++g) {
            int pn = (((g + 1) & 127) << 6) + lane;
            float nx = l_xyz[3 * pn + 0];
            float ny = l_xyz[3 * pn + 1];
            float nz = l_xyz[3 * pn + 2];
            float dx = qx - cx, dy = qy - cy, dz = qz - cz;
            float d2 = dx * dx + dy * dy + dz * dz;
            bool valid = d2 < r2;
            unsigned long long mask = __ballot(valid);
            if (cnt == 0 && mask) first_idx = (g << 6) + (int)__builtin_ctzll(mask);
            int pos = cnt + __popcll(mask & ((1ull << lane) - 1ull));
            if (valid && pos < NS) idx_out[q * NS + pos] = (g << 6) + lane;
            cnt += __popcll(mask);
            cx = nx; cy = ny; cz = nz;
        }
        if (cnt == 0) {
            if (lane < NS) idx_out[q * NS + lane] = 0;
            if (lane == 0) empty_out[q] = 1;
        } else {
            int filled = cnt < NS ? cnt : NS;
            if (lane >= filled && lane < NS) idx_out[q * NS + lane] = first_idx;
            if (lane == 0) empty_out[q] = 0;
        }
    }
}

// ============ register-tiled MLP layers: lane=row, acc[ch] in VGPRs ========

// f-branch layer 0: gather (idx_d) -> 35x64 matmul -> x0f + stats partials
__global__ void mlp_f0_kernel(const float* __restrict__ xyz, const float* __restrict__ feats,
                              const float* __restrict__ newxyz, const float* __restrict__ W) {
    __shared__ float buf[256 * 65];   // in-tile pad 37 / out-tile pad 65 (66.6 KB)
    __shared__ float ls[256], lq[256];
    int tid = threadIdx.x;
    int rowbase = blockIdx.x * 256;
    {
        int row = rowbase + tid;
        int q = row >> 5, b = q >> 12;
        float* dst = &buf[tid * 37];
        if (g_empty_d[q]) {
#pragma unroll
            for (int c = 0; c < 35; ++c) dst[c] = 0.f;
        } else {
            int idx = g_idx_d[row];
            const float* xp = xyz + (size_t)b * NPTS * 3 + idx * 3;
            dst[0] = xp[0] - newxyz[q * 3 + 0];
            dst[1] = xp[1] - newxyz[q * 3 + 1];
            dst[2] = xp[2] - newxyz[q * 3 + 2];
            const float4* fp = (const float4*)(feats + (size_t)b * NPTS * CIN + (size_t)idx * CIN);
#pragma unroll
            for (int j = 0; j < 8; ++j) {
                float4 v = fp[j];
                dst[3 + 4 * j + 0] = v.x; dst[3 + 4 * j + 1] = v.y;
                dst[3 + 4 * j + 2] = v.z; dst[3 + 4 * j + 3] = v.w;
            }
        }
    }
    int w = tid >> 6, lane = tid & 63;
    const float* inrow = &buf[tid * 37];
    float acc[64];
#pragma unroll
    for (int ch = 0; ch < 64; ++ch) acc[ch] = 0.f;
    for (int c = 0; c < 35; ++c) {
        float h = inrow[c];
#pragma unroll
        for (int ch = 0; ch < 64; ++ch) acc[ch] = fmaf(h, W[c * 64 + ch], acc[ch]);
    }
    __syncthreads();
    float* orow = &buf[tid * 65];
#pragma unroll
    for (int ch = 0; ch < 64; ++ch) orow[ch] = acc[ch];
    float sum = 0.f, sq = 0.f;
    for (int r = 0; r < 64; ++r) {
        float v = buf[(w * 64 + r) * 65 + lane];
        g_x0f[(size_t)(rowbase + w * 64 + r) * 64 + lane] = v;
        sum += v; sq += v * v;
    }
    ls[tid] = sum; lq[tid] = sq; __syncthreads();
    if (tid < 64) {
        g_psT[tid * 1024 + blockIdx.x] = ls[tid] + ls[64 + tid] + ls[128 + tid] + ls[192 + tid];
        g_pqT[tid * 1024 + blockIdx.x] = lq[tid] + lq[64 + tid] + lq[128 + tid] + lq[192 + tid];
    }
}

// f-branch layer 1: BN+ReLU(x0f) -> 64x64 matmul -> x1f + stats partials
__global__ void mlp_f1_kernel(const float* __restrict__ W) {
    __shared__ float buf[256 * 65];
    __shared__ float ls[256], lq[256];
    int tid = threadIdx.x;
    int rowbase = blockIdx.x * 256;
    const float4* src = (const float4*)g_x0f;
#pragma unroll
    for (int k = 0; k < 16; ++k) {
        int o4 = tid + k * 256;
        float4 v = src[(size_t)rowbase * 16 + o4];
        int o = o4 * 4, row = o >> 6, c = o & 63;
        float* d = &buf[row * 65 + c];
        d[0] = v.x; d[1] = v.y; d[2] = v.z; d[3] = v.w;
    }
    __syncthreads();
    int w = tid >> 6, lane = tid & 63;
    const float* inrow = &buf[tid * 65];
    float acc[64];
#pragma unroll
    for (int ch = 0; ch < 64; ++ch) acc[ch] = 0.f;
    for (int c = 0; c < 64; ++c) {
        float h = fmaxf(fmaf(inrow[c], g_bnscale[2][c], g_bnshift[2][c]), 0.f);
#pragma unroll
        for (int ch = 0; ch < 64; ++ch) acc[ch] = fmaf(h, W[c * 64 + ch], acc[ch]);
    }
    float* orow = &buf[tid * 65];
#pragma unroll
    for (int ch = 0; ch < 64; ++ch) orow[ch] = acc[ch];
    float sum = 0.f, sq = 0.f;
    for (int r = 0; r < 64; ++r) {
        float v = buf[(w * 64 + r) * 65 + lane];
        g_x1f[(size_t)(rowbase + w * 64 + r) * 64 + lane] = v;
        sum += v; sq += v * v;
    }
    ls[tid] = sum; lq[tid] = sq; __syncthreads();
    if (tid < 64) {
        g_psT[tid * 1024 + blockIdx.x] = ls[tid] + ls[64 + tid] + ls[128 + tid] + ls[192 + tid];
        g_pqT[tid * 1024 + blockIdx.x] = lq[tid] + lq[64 + tid] + lq[128 + tid] + lq[192 + tid];
    }
}

// p-branch layer 0: gather (idx_p) -> 35x32 matmul -> x0p + stats partials
__global__ void mlp_p0_kernel(const float* __restrict__ xyz, const float* __restrict__ feats,
                              const float* __restrict__ newxyz, const float* __restrict__ W) {
    __shared__ float buf[256 * 37];
    __shared__ float ls[256], lq[256];
    int tid = threadIdx.x;
    int rowbase = blockIdx.x * 256;
    {
        int row = rowbase + tid;
        int q = row >> 4, b = q >> 12;
        float* dst = &buf[tid * 37];
        if (g_empty_p[q]) {
#pragma unroll
            for (int c = 0; c < 35; ++c) dst[c] = 0.f;
        } else {
            int idx = g_idx_p[row];
            const float* xp = xyz + (size_t)b * NPTS * 3 + idx * 3;
            dst[0] = xp[0] - newxyz[q * 3 + 0];
            dst[1] = xp[1] - newxyz[q * 3 + 1];
            dst[2] = xp[2] - newxyz[q * 3 + 2];
            const float4* fp = (const float4*)(feats + (size_t)b * NPTS * CIN + (size_t)idx * CIN);
#pragma unroll
            for (int j = 0; j < 8; ++j) {
                float4 v = fp[j];
                dst[3 + 4 * j + 0] = v.x; dst[3 + 4 * j + 1] = v.y;
                dst[3 + 4 * j + 2] = v.z; dst[3 + 4 * j + 3] = v.w;
            }
        }
    }
    int w = tid >> 6, lane = tid & 63;
    const float* inrow = &buf[tid * 37];
    float acc[32];
#pragma unroll
    for (int ch = 0; ch < 32; ++ch) acc[ch] = 0.f;
    for (int c = 0; c < 35; ++c) {
        float h = inrow[c];
#pragma unroll
        for (int ch = 0; ch < 32; ++ch) acc[ch] = fmaf(h, W[c * 32 + ch], acc[ch]);
    }
    __syncthreads();
    float* orow = &buf[tid * 33];
#pragma unroll
    for (int ch = 0; ch < 32; ++ch) orow[ch] = acc[ch];
    float sum = 0.f, sq = 0.f;
    int rh = lane >> 5, cl = lane & 31;
    for (int r = 0; r < 32; ++r) {
        float v = buf[(w * 64 + r * 2 + rh) * 33 + cl];
        g_x0p[(size_t)(rowbase + w * 64 + r * 2) * 32 + lane] = v;
        sum += v; sq += v * v;
    }
    ls[tid] = sum; lq[tid] = sq; __syncthreads();
    if (tid < 32) {
        float s = 0.f, qq = 0.f;
#pragma unroll
        for (int k = 0; k < 8; ++k) { s += ls[tid + 32 * k]; qq += lq[tid + 32 * k]; }
        g_psT[tid * 1024 + blockIdx.x] = s;
        g_pqT[tid * 1024 + blockIdx.x] = qq;
    }
}

// p-branch layer 1: BN+ReLU(x0p) -> 32x32 matmul -> x1p + stats partials
__global__ void mlp_p1_kernel(const float* __restrict__ W) {
    __shared__ float buf[256 * 33];
    __shared__ float ls[256], lq[256];
    int tid = threadIdx.x;
    int rowbase = blockIdx.x * 256;
    const float4* src = (const float4*)g_x0p;
#pragma unroll
    for (int k = 0; k < 8; ++k) {
        int o4 = tid + k * 256;
        float4 v = src[(size_t)rowbase * 8 + o4];
        int o = o4 * 4, row = o >> 5, c = o & 31;
        float* d = &buf[row * 33 + c];
        d[0] = v.x; d[1] = v.y; d[2] = v.z; d[3] = v.w;
    }
    __syncthreads();
    int w = tid >> 6, lane = tid & 63;
    const float* inrow = &buf[tid * 33];
    float acc[32];
#pragma unroll
    for (int ch = 0; ch < 32; ++ch) acc[ch] = 0.f;
    for (int c = 0; c < 32; ++c) {
        float h = fmaxf(fmaf(inrow[c], g_bnscale[0][c], g_bnshift[0][c]), 0.f);
#pragma unroll
        for (int ch = 0; ch < 32; ++ch) acc[ch] = fmaf(h, W[c * 32 + ch], acc[ch]);
    }
    float* orow = &buf[tid * 33];
#pragma unroll
    for (int ch = 0; ch < 32; ++ch) orow[ch] = acc[ch];
    float sum = 0.f, sq = 0.f;
    int rh = lane >> 5, cl = lane & 31;
    for (int r = 0; r < 32; ++r) {
        float v = buf[(w * 64 + r * 2 + rh) * 33 + cl];
        g_x1p[(size_t)(rowbase + w * 64 + r * 2) * 32 + lane] = v;
        sum += v; sq += v * v;
    }
    ls[tid] = sum; lq[tid] = sq; __syncthreads();
    if (tid < 32) {
        float s = 0.f, qq = 0.f;
#pragma unroll
        for (int k = 0; k < 8; ++k) { s += ls[tid + 32 * k]; qq += lq[tid + 32 * k]; }
        g_psT[tid * 1024 + blockIdx.x] = s;
        g_pqT[tid * 1024 + blockIdx.x] = qq;
    }
}

// -------- BN stats finalize: one block per channel, coalesced, tree-reduce --
__global__ void finalize_kernel(const float* __restrict__ gamma, const float* __restrict__ beta,
                                float n, int layer, int nblocks) {
    __shared__ double l_s[256], l_q[256];
    int ch = blockIdx.x, tid = threadIdx.x;
    double s = 0, q = 0;
    for (int i = tid; i < nblocks; i += 256) { s += g_psT[ch * 1024 + i]; q += g_pqT[ch * 1024 + i]; }
    l_s[tid] = s; l_q[tid] = q; __syncthreads();
    for (int off = 128; off > 0; off >>= 1) {
        if (tid < off) { l_s[tid] += l_s[tid + off]; l_q[tid] += l_q[tid + off]; }
        __syncthreads();
    }
    if (tid == 0) {
        double mu = l_s[0] / (double)n;
        double var = l_q[0] / (double)n - mu * mu;
        if (var < 0) var = 0;
        double sc = (double)gamma[ch] / sqrt(var + 1e-5);
        g_bnscale[layer][ch] = (float)sc;
        g_bnshift[layer][ch] = (float)((double)beta[ch] - mu * sc);
    }
}

// ---------------- pooled max + per-query partial dot with fcw --------------
__global__ void pool_fc_kernel(const float* __restrict__ fcw) {
    int tid = threadIdx.x;
    int q = blockIdx.x * 8 + (tid >> 5);
    int ch = tid & 31;
    float sc = g_bnscale[1][ch], sh = g_bnshift[1][ch];
    float m = 0.f;
    for (int s = 0; s < SP; ++s) {
        float v = g_x1p[(size_t)(q * SP + s) * CP + ch] * sc + sh;
        m = fmaxf(m, fmaxf(v, 0.f));
    }
    float pd = m * fcw[(q & 63) * CP + ch];
    for (int off = 16; off > 0; off >>= 1) pd += __shfl_down(pd, off, 32);
    if (ch == 0) g_pdot[q] = pd;
}

// ---------------- per-roi fc reduce -> deform radius -----------------------
__global__ void roi_r_kernel(const float* __restrict__ roif, const float* __restrict__ fcw,
                             const float* __restrict__ fcb) {
    int tid = threadIdx.x;
    int roi = blockIdx.x * 4 + (tid >> 6);
    int lane = tid & 63;
    float acc = g_pdot[roi * 64 + lane]
              + roif[roi * 128 + lane]      * fcw[2048 + lane]
              + roif[roi * 128 + 64 + lane] * fcw[2048 + 64 + lane];
    for (int off = 32; off > 0; off >>= 1) acc += __shfl_down(acc, off, 64);
    if (lane == 0) {
        float res = acc + fcb[0];
        g_rroi[roi] = fmaxf(res / DIV_COEF_C + RADIUS_C, MIN_R_C);
    }
}

// ---------------- final: sigmoid weights * BN+ReLU(x1f), max over S --------
__global__ void final_kernel(const float* __restrict__ xyz, const float* __restrict__ newxyz,
                             const float* __restrict__ td, float* __restrict__ out) {
    __shared__ float  lw[2][32];
    __shared__ float4 lp[2][8][16];
    int tid = threadIdx.x;
    int qpair = blockIdx.x * 2;
    float temp = td[0];
    if (tid < 64) {
        int ql = tid >> 5, s = tid & 31;
        int q = qpair + ql;
        float wv = 0.f;
        if (!g_empty_d[q]) {
            int idx = g_idx_d[q * SD + s];
            int b = q >> 12;
            float dx = xyz[(size_t)b * NPTS * 3 + idx * 3 + 0] - newxyz[q * 3 + 0];
            float dy = xyz[(size_t)b * NPTS * 3 + idx * 3 + 1] - newxyz[q * 3 + 1];
            float dz = xyz[(size_t)b * NPTS * 3 + idx * 3 + 2] - newxyz[q * 3 + 2];
            float dist = sqrtf(dx * dx + dy * dy + dz * dz);
            float rq = g_rroi[q >> 6];
            wv = 1.f / (1.f + expf(-(rq - dist) / temp));
        }
        lw[ql][s] = wv;
    }
    __syncthreads();
    {
        int ql = tid >> 7, u = tid & 127;
        int ch4 = u & 15, sg = u >> 4;
        int q = qpair + ql;
        const float4* x4 = (const float4*)g_x1f;
        const float4* sc4 = (const float4*)g_bnscale[3];
        const float4* sh4 = (const float4*)g_bnshift[3];
        float4 SC = sc4[ch4], SH = sh4[ch4];
        float4 m = make_float4(0.f, 0.f, 0.f, 0.f);
#pragma unroll
        for (int k = 0; k < 4; ++k) {
            int s = sg * 4 + k;
            float4 x = x4[((size_t)q * SD + s) * 16 + ch4];
            float ws = lw[ql][s];
            m.x = fmaxf(m.x, ws * fmaxf(fmaf(x.x, SC.x, SH.x), 0.f));
            m.y = fmaxf(m.y, ws * fmaxf(fmaf(x.y, SC.y, SH.y), 0.f));
            m.z = fmaxf(m.z, ws * fmaxf(fmaf(x.z, SC.z, SH.z), 0.f));
            m.w = fmaxf(m.w, ws * fmaxf(fmaf(x.w, SC.w, SH.w), 0.f));
        }
        lp[ql][sg][ch4] = m;
    }
    __syncthreads();
    if (tid < 128) {
        int ql = tid >> 6, ch = tid & 63;
        const float* base = (const float*)&lp[ql][0][0];
        float mm = 0.f;
#pragma unroll
        for (int sg = 0; sg < 8; ++sg) mm = fmaxf(mm, base[sg * 64 + ch]);
        out[MTOT * 3 + (size_t)(qpair + ql) * CF + ch] = mm;
    }
}

extern "C" void kernel_launch(void* const* d_in, const int* in_sizes, int n_in,
                              void* d_out, int out_size, void* d_ws, size_t ws_size,
                              hipStream_t stream) {
    const float* xyz   = (const float*)d_in[0];
    const float* feats = (const float*)d_in[1];
    const float* rois  = (const float*)d_in[2];
    const float* roif  = (const float*)d_in[3];
    const float* td    = (const float*)d_in[4];
    const float* pw0 = (const float*)d_in[5];
    const float* pg0 = (const float*)d_in[6];
    const float* pb0 = (const float*)d_in[7];
    const float* pw1 = (const float*)d_in[8];
    const float* pg1 = (const float*)d_in[9];
    const float* pb1 = (const float*)d_in[10];
    const float* fw0 = (const float*)d_in[11];
    const float* fg0 = (const float*)d_in[12];
    const float* fb0 = (const float*)d_in[13];
    const float* fw1 = (const float*)d_in[14];
    const float* fg1 = (const float*)d_in[15];
    const float* fb1 = (const float*)d_in[16];
    const float* fcw = (const float*)d_in[17];
    const float* fcb = (const float*)d_in[18];
    float* out = (float*)d_out;

    copy_xyz_kernel<<<96, 256, 0, stream>>>(rois, out);

    // pred branch
    bq_kernel<SP><<<256, 1024, 0, stream>>>(xyz, rois);
    mlp_p0_kernel<<<512, 256, 0, stream>>>(xyz, feats, rois, pw0);
    finalize_kernel<<<CP, 256, 0, stream>>>(pg0, pb0, (float)(MTOT * SP), 0, 512);
    mlp_p1_kernel<<<512, 256, 0, stream>>>(pw1);
    finalize_kernel<<<CP, 256, 0, stream>>>(pg1, pb1, (float)(MTOT * SP), 1, 512);
    pool_fc_kernel<<<MTOT / 8, 256, 0, stream>>>(fcw);
    roi_r_kernel<<<NROI / 4, 256, 0, stream>>>(roif, fcw, fcb);

    // deform branch
    bq_kernel<SD><<<256, 1024, 0, stream>>>(xyz, rois);
    mlp_f0_kernel<<<1024, 256, 0, stream>>>(xyz, feats, rois, fw0);
    finalize_kernel<<<CF, 256, 0, stream>>>(fg0, fb0, (float)(MTOT * SD), 2, 1024);
    mlp_f1_kernel<<<1024, 256, 0, stream>>>(fw1);
    finalize_kernel<<<CF, 256, 0, stream>>>(fg1, fb1, (float)(MTOT * SD), 3, 1024);
    final_kernel<<<MTOT / 2, 256, 0, stream>>>(xyz, rois, td, out);
}